// Round 7
// baseline (154.593 us; speedup 1.0000x reference)
//
#include <hip/hip_runtime.h>

#define NROW 8192
#define DIM  256
#define INV_T 5.0f
#define BM 128
#define BN 128

typedef _Float16 f16x8 __attribute__((ext_vector_type(8)));
typedef _Float16 f16x4 __attribute__((ext_vector_type(4)));
typedef float    f32x4 __attribute__((ext_vector_type(4)));
typedef unsigned long long u64;

__device__ __forceinline__ void gload_lds16(const void* g, void* l) {
  __builtin_amdgcn_global_load_lds(
      (__attribute__((address_space(1))) void*)(g),
      (__attribute__((address_space(3))) void*)(l),
      16, 0, 0);
}

// ---------------- normalize rows + convert to fp16 ----------------
__global__ __launch_bounds__(256) void norm_kernel(
    const float* __restrict__ zv, const float* __restrict__ zf,
    _Float16* __restrict__ ov, _Float16* __restrict__ of) {
  const float* in  = blockIdx.y ? zf : zv;
  _Float16*    out = blockIdx.y ? of : ov;
  int row  = blockIdx.x * 4 + (threadIdx.x >> 6);
  int lane = threadIdx.x & 63;
  float4 v = ((const float4*)(in + (size_t)row * DIM))[lane];
  float ss = v.x * v.x + v.y * v.y + v.z * v.z + v.w * v.w;
#pragma unroll
  for (int off = 1; off < 64; off <<= 1) ss += __shfl_xor(ss, off);
  float inv = 1.0f / fmaxf(sqrtf(ss), 1e-12f);
  f16x4 o;
  o.x = (_Float16)(v.x * inv);
  o.y = (_Float16)(v.y * inv);
  o.z = (_Float16)(v.z * inv);
  o.w = (_Float16)(v.w * inv);
  ((f16x4*)(out + (size_t)row * DIM))[lane] = o;
}

// ---------------- main kernel: G-blocks (dense GEMM+exp) + S-blocks (Gf->bitmask) ----
// bid: cb = bid&7 (XCD-affine column slice), kind = (bid>>3)&1, rb = bid>>4 (0..63).
// G: rows [rb*128,+128) x cols [cb*1024,+1024), dense E partials. No Gf coupling.
// S: same region streamed from Gf, ballot-packed to a bitmask. No barriers.
__global__ __launch_bounds__(256, 2) void main_kernel(
    const _Float16* __restrict__ zv, const _Float16* __restrict__ zf,
    const float* __restrict__ Gf,
    float* __restrict__ Ep, u64* __restrict__ Mask) {

  __shared__ __align__(16) _Float16 Asf[BM * DIM];      // 64 KB
  __shared__ __align__(16) _Float16 Bs[2][BN * 32];     // 16 KB

  const int bid  = blockIdx.x;
  const int cb   = bid & 7;
  const int kind = (bid >> 3) & 1;
  const int rb   = bid >> 4;
  const int t_   = threadIdx.x;
  const int lane = t_ & 63;
  const int row0 = rb * BM;
  const int col0 = cb * 1024;

  if (kind == 0) {
    // =================== G-block: dense E_i partials (R1 structure, mask-free) =========
    const int w   = t_ >> 6;
    const int wr  = w >> 1;
    const int wc  = w & 1;
    const int l15 = lane & 15;
    const int kq  = lane >> 4;

#pragma unroll
    for (int c = 0; c < 16; ++c) {
      int i = c * 256 + t_;
      int row = i >> 5, cbP = i & 31;
      int cbL = cbP ^ (row & 7);
      gload_lds16(zv + (size_t)(row0 + row) * DIM + cbL * 8,
                  &Asf[(size_t)(c * 256 + w * 64) * 8]);
    }

    auto stageB = [&](int buf, int s) {
      int tt = s >> 3, kk = s & 7;
      int ct0 = col0 + tt * BN;
      int k0 = kk * 32;
#pragma unroll
      for (int c = 0; c < 2; ++c) {
        int i = c * 256 + t_;
        int row = i >> 2, cbP = i & 3;
        int cbL = cbP ^ ((row >> 1) & 3);
        gload_lds16(zf + (size_t)(ct0 + row) * DIM + k0 + cbL * 8,
                    &Bs[buf][(size_t)(c * 256 + w * 64) * 8]);
      }
    };

    stageB(0, 0);
    asm volatile("s_waitcnt vmcnt(0)" ::: "memory");
    __syncthreads();

    f32x4 acc[4][4];
    float Sa[16];
#pragma unroll
    for (int i = 0; i < 16; ++i) Sa[i] = 0.0f;

#pragma unroll 2
    for (int s = 0; s < 64; ++s) {
      const int cur = s & 1;
      if ((s & 7) == 0) {
#pragma unroll
        for (int m = 0; m < 4; ++m)
#pragma unroll
          for (int n = 0; n < 4; ++n) acc[m][n] = (f32x4)(0.0f);
      }
      if (s < 63) stageB(cur ^ 1, s + 1);

      const int k0 = (s & 7) * 32;
      f16x8 af[4], bf[4];
#pragma unroll
      for (int m = 0; m < 4; ++m) {
        int row = wr * 64 + m * 16 + l15;
        int cbL = (k0 >> 3) + kq;
        int cbP = cbL ^ (row & 7);
        af[m] = *(const f16x8*)&Asf[(size_t)row * 256 + cbP * 8];
      }
#pragma unroll
      for (int n = 0; n < 4; ++n) {
        int row = wc * 64 + n * 16 + l15;
        int cbP = kq ^ ((row >> 1) & 3);
        bf[n] = *(const f16x8*)&Bs[cur][(size_t)row * 32 + cbP * 8];
      }
#pragma unroll
      for (int m = 0; m < 4; ++m)
#pragma unroll
        for (int n = 0; n < 4; ++n)
          acc[m][n] = __builtin_amdgcn_mfma_f32_16x16x32_f16(af[m], bf[n], acc[m][n], 0, 0, 0);

      if ((s & 7) == 7) {
#pragma unroll
        for (int m = 0; m < 4; ++m)
#pragma unroll
          for (int n = 0; n < 4; ++n)
#pragma unroll
            for (int r = 0; r < 4; ++r)
              Sa[m * 4 + r] += __expf(acc[m][n][r] * INV_T);
      }
      asm volatile("s_waitcnt vmcnt(0)" ::: "memory");
      __syncthreads();
    }

#pragma unroll
    for (int off = 1; off <= 8; off <<= 1)
#pragma unroll
      for (int i = 0; i < 16; ++i) Sa[i] += __shfl_xor(Sa[i], off);

    const int slot = cb * 2 + wc;   // 16 slots
#pragma unroll
    for (int i = 0; i < 16; ++i) {
      if (l15 == i) {
        int m = i >> 2, r = i & 3;
        int row = row0 + wr * 64 + m * 16 + kq * 4 + r;
        Ep[(size_t)slot * NROW + row] = Sa[i];
      }
    }
  } else {
    // =================== S-block: Gf -> bitmask, pure stream, no barriers =============
    // wave wv handles rows r0, r0+4, ..., r0+124 (r0 = row0 + wv).
    // Per row: 4 segments of 256 cols; lane reads float4 at col s*256+lane*4.
    // Mask layout: word[(row*32 + cb*4 + s)*4 + c], bit L <-> col (cb*4+s)*256 + L*4 + c.
    const int wv  = t_ >> 6;
    const int r0  = row0 + wv;
    const float* gb = Gf + (size_t)r0 * NROW + col0 + lane * 4;
    u64* mb = Mask + ((size_t)r0 * 32 + cb * 4) * 4;

    float4 ring[4][4];

#define SISSUE(K, SLOT)                                                        \
  do {                                                                         \
    const float* p_ = gb + (size_t)(4 * (K)) * NROW;                           \
    _Pragma("unroll") for (int s = 0; s < 4; ++s)                              \
        ring[SLOT][s] = *(const float4*)(p_ + s * 256);                        \
  } while (0)

#define SPACK(K, SLOT)                                                         \
  do {                                                                         \
    u64* mw_ = mb + (size_t)(4 * (K)) * 128;                                   \
    _Pragma("unroll") for (int s = 0; s < 4; ++s) {                            \
      float4 q_ = ring[SLOT][s];                                               \
      u64 w0_ = __ballot(q_.x > 0.0f), w1_ = __ballot(q_.y > 0.0f);            \
      u64 w2_ = __ballot(q_.z > 0.0f), w3_ = __ballot(q_.w > 0.0f);            \
      u64 myw_ = (lane & 1) ? ((lane & 2) ? w3_ : w1_)                         \
                            : ((lane & 2) ? w2_ : w0_);                        \
      if (lane < 4) mw_[s * 4 + lane] = myw_;                                  \
    }                                                                          \
  } while (0)

    SISSUE(0, 0); SISSUE(1, 1); SISSUE(2, 2);
    asm volatile("" ::: "memory");
#pragma unroll 1
    for (int kk = 0; kk < 8; ++kk) {
      int k0i = kk * 4;
      if (k0i + 3 < 32) SISSUE(k0i + 3, 3);
      asm volatile("" ::: "memory");
      SPACK(k0i + 0, 0);
      if (k0i + 4 < 32) SISSUE(k0i + 4, 0);
      asm volatile("" ::: "memory");
      SPACK(k0i + 1, 1);
      if (k0i + 5 < 32) SISSUE(k0i + 5, 1);
      asm volatile("" ::: "memory");
      SPACK(k0i + 2, 2);
      if (k0i + 6 < 32) SISSUE(k0i + 6, 2);
      asm volatile("" ::: "memory");
      SPACK(k0i + 3, 3);
    }
#undef SISSUE
#undef SPACK
  }
}

// ---------------- sparse pass: bitmask -> per-row P, E_pos, C (deterministic) -------
__global__ __launch_bounds__(256) void sparse_kernel(
    const _Float16* __restrict__ zv, const _Float16* __restrict__ zf,
    const u64* __restrict__ Mask,
    float* __restrict__ Pr, float* __restrict__ Er, float* __restrict__ Cr) {
  const int i    = blockIdx.x * 4 + (threadIdx.x >> 6);
  const int lane = threadIdx.x & 63;
  f16x4 a16 = *(const f16x4*)(zv + (size_t)i * DIM + lane * 4);
  const float a0 = (float)a16[0], a1 = (float)a16[1];
  const float a2 = (float)a16[2], a3 = (float)a16[3];
  const u64* mb = Mask + (size_t)i * 128;
  u64 m0 = mb[lane];
  u64 m1 = mb[64 + lane];
  float P = 0.0f, E = 0.0f, C = 0.0f;
  bool dseen = false;
#pragma unroll 1
  for (int g = 0; g < 128; ++g) {
    u64 wd = __shfl((g < 64) ? m0 : m1, g & 63);
    while (wd) {
      int b = (int)__builtin_ctzll(wd);
      wd &= wd - 1;
      int j = (g >> 2) * 256 + b * 4 + (g & 3);
      f16x4 b16 = *(const f16x4*)(zf + (size_t)j * DIM + lane * 4);
      float d = a0 * (float)b16[0] + a1 * (float)b16[1] +
                a2 * (float)b16[2] + a3 * (float)b16[3];
#pragma unroll
      for (int off = 1; off < 64; off <<= 1) d += __shfl_xor(d, off);
      float sim = d * INV_T;
      P += sim;
      E += __expf(sim);
      C += 1.0f;
      dseen = dseen || (j == i);
    }
  }
  if (!dseen) {   // diagonal not in Gf: append (fixed order -> deterministic)
    f16x4 b16 = *(const f16x4*)(zf + (size_t)i * DIM + lane * 4);
    float d = a0 * (float)b16[0] + a1 * (float)b16[1] +
              a2 * (float)b16[2] + a3 * (float)b16[3];
#pragma unroll
    for (int off = 1; off < 64; off <<= 1) d += __shfl_xor(d, off);
    float sim = d * INV_T;
    P += sim;
    E += __expf(sim);
    C += 1.0f;
  }
  if (lane == 0) { Pr[i] = P; Er[i] = E; Cr[i] = C; }
}

// ---------------- per-row loss + block partials (deterministic) ----------------
__global__ __launch_bounds__(256) void loss_partial_kernel(
    const float* __restrict__ Ep, const float* __restrict__ Pr,
    const float* __restrict__ Er, const float* __restrict__ Cr,
    float* __restrict__ bsum) {
  int row = blockIdx.x * 256 + threadIdx.x;
  float E = 0.0f;
#pragma unroll
  for (int s2 = 0; s2 < 16; ++s2) E += Ep[(size_t)s2 * NROW + row];
  float P = Pr[row], sE = Er[row], C = Cr[row];
  float S = E - sE + C;                 // neg exps + exp(0) per pos slot
  float pos = P / (C + 1e-8f);
  float contrib = __logf(S + __expf(pos)) - pos;
#pragma unroll
  for (int off = 1; off < 64; off <<= 1) contrib += __shfl_xor(contrib, off);
  __shared__ float wsum[4];
  if ((threadIdx.x & 63) == 0) wsum[threadIdx.x >> 6] = contrib;
  __syncthreads();
  if (threadIdx.x == 0) bsum[blockIdx.x] = wsum[0] + wsum[1] + wsum[2] + wsum[3];
}

__global__ void loss_final_kernel(const float* __restrict__ bsum, float* __restrict__ out) {
  int lane = threadIdx.x;
  float v = (lane < 32) ? bsum[lane] : 0.0f;
#pragma unroll
  for (int off = 1; off < 64; off <<= 1) v += __shfl_xor(v, off);
  if (lane == 0) out[0] = v / (float)NROW;
}

extern "C" void kernel_launch(void* const* d_in, const int* in_sizes, int n_in,
                              void* d_out, int out_size, void* d_ws, size_t ws_size,
                              hipStream_t stream) {
  const float* zv = (const float*)d_in[0];
  const float* zf = (const float*)d_in[1];
  const float* Gf = (const float*)d_in[2];
  float* out = (float*)d_out;

  char* ws = (char*)d_ws;
  _Float16* zv16 = (_Float16*)ws;                                   // 4 MB
  _Float16* zf16 = zv16 + (size_t)NROW * DIM;                       // 4 MB
  float* Ep = (float*)(ws + (8u << 20));                            // 512 KB
  float* Pr = (float*)(ws + (9u << 20));
  float* Er = Pr + NROW;
  float* Cr = Er + NROW;
  float* bsum = Cr + NROW;                                          // 32 floats
  u64* Mask = (u64*)(ws + (16u << 20));                             // 8 MB

  norm_kernel<<<dim3(NROW / 4, 2), 256, 0, stream>>>(zv, zf, zv16, zf16);
  main_kernel<<<1024, 256, 0, stream>>>(zv16, zf16, Gf, Ep, Mask);
  sparse_kernel<<<NROW / 4, 256, 0, stream>>>(zv16, zf16, Mask, Pr, Er, Cr);
  loss_partial_kernel<<<NROW / 256, 256, 0, stream>>>(Ep, Pr, Er, Cr, bsum);
  loss_final_kernel<<<1, 64, 0, stream>>>(bsum, out);
}

// Round 8
// 103.018 us; speedup vs baseline: 1.5006x; 1.5006x over previous
//
#include <hip/hip_runtime.h>

#define NROW 8192
#define DIM  256
#define INV_T 5.0f
#define BM 128
#define BN 128
#define CSPLIT 8
#define COLS_PER_BLOCK (NROW / CSPLIT)   // 1024
#define NT 8                              // column tiles per block

typedef _Float16 f16x8 __attribute__((ext_vector_type(8)));
typedef _Float16 f16x4 __attribute__((ext_vector_type(4)));
typedef float    f32x4 __attribute__((ext_vector_type(4)));
typedef unsigned long long u64;

__device__ __forceinline__ void gload_lds16(const void* g, void* l) {
  __builtin_amdgcn_global_load_lds(
      (__attribute__((address_space(1))) void*)(g),
      (__attribute__((address_space(3))) void*)(l),
      16, 0, 0);
}

// ---------------- normalize rows + convert to fp16 ----------------
__global__ __launch_bounds__(256) void norm_kernel(
    const float* __restrict__ zv, const float* __restrict__ zf,
    _Float16* __restrict__ ov, _Float16* __restrict__ of) {
  const float* in  = blockIdx.y ? zf : zv;
  _Float16*    out = blockIdx.y ? of : ov;
  int row  = blockIdx.x * 4 + (threadIdx.x >> 6);
  int lane = threadIdx.x & 63;
  float4 v = ((const float4*)(in + (size_t)row * DIM))[lane];
  float ss = v.x * v.x + v.y * v.y + v.z * v.z + v.w * v.w;
#pragma unroll
  for (int off = 1; off < 64; off <<= 1) ss += __shfl_xor(ss, off);
  float inv = 1.0f / fmaxf(sqrtf(ss), 1e-12f);
  f16x4 o;
  o.x = (_Float16)(v.x * inv);
  o.y = (_Float16)(v.y * inv);
  o.z = (_Float16)(v.z * inv);
  o.w = (_Float16)(v.w * inv);
  ((f16x4*)(out + (size_t)row * DIM))[lane] = o;
}

// ---------------- fused GEMM + ballot-packed mask + exp/row-reductions ----------------
// Flat grid 512, cb = bid&7: XCD-affine column slices (round-robin dispatch) so each
// XCD's 64 blocks share one 512 KB zf16 slice (L2-resident) against the Gf stream.
__global__ __launch_bounds__(256, 2) void fused_kernel(
    const _Float16* __restrict__ zv, const _Float16* __restrict__ zf,
    const float* __restrict__ Gf,
    float* __restrict__ Sp, float* __restrict__ Pp, float* __restrict__ Cp) {

  __shared__ __align__(16) _Float16 Asf[BM * DIM];      // 64 KB, XOR-swizzled
  __shared__ __align__(16) _Float16 Bs[2][BN * 32];     // 2 x 8 KB, XOR-swizzled

  const int t_   = threadIdx.x;
  const int lane = t_ & 63;
  const int w    = t_ >> 6;
  const int wr   = w >> 1;
  const int wc   = w & 1;
  const int l15  = lane & 15;
  const int kq   = lane >> 4;
  const int rb   = blockIdx.x >> 3;
  const int cb   = blockIdx.x & 7;       // = XCD id under round-robin dispatch
  const int row0 = rb * BM;
  const int col0 = cb * COLS_PER_BLOCK;

  // ---- stage full A tile (128 x 256 fp16), source pre-swizzled ----
#pragma unroll
  for (int c = 0; c < 16; ++c) {
    int i = c * 256 + t_;
    int row = i >> 5, cbP = i & 31;
    int cbL = cbP ^ (row & 7);
    gload_lds16(zv + (size_t)(row0 + row) * DIM + cbL * 8,
                &Asf[(size_t)(c * 256 + w * 64) * 8]);
  }

  auto stageB = [&](int buf, int s) {
    int tt = s >> 3, kk = s & 7;
    int ct0 = col0 + tt * BN;
    int k0 = kk * 32;
#pragma unroll
    for (int c = 0; c < 2; ++c) {
      int i = c * 256 + t_;
      int row = i >> 2, cbP = i & 3;
      int cbL = cbP ^ ((row >> 1) & 3);
      gload_lds16(zf + (size_t)(ct0 + row) * DIM + k0 + cbL * 8,
                  &Bs[buf][(size_t)(c * 256 + w * 64) * 8]);
    }
  };

  // Gf staging: wave (wr,wc) owns the 64x64 sub-tile rows [wr*64,+64) x cols [wc*64,+64).
  auto issueGf = [&](float4* q, int tt, int c0) {
    const float* base = Gf + (size_t)(row0 + wr * 64 + (lane >> 4)) * NROW
                           + col0 + tt * BN + wc * 64 + l15 * 4;
#pragma unroll
    for (int j = 0; j < 4; ++j)
      q[j] = *(const float4*)(base + (size_t)((c0 + j) * 4) * NROW);
  };

  // Ballot-pack 4 chunks (a 16-row group = one m block) into this lane's mask word.
  // Consumer bit for (m,n,r) is bit (r*16 + n*4) of wm[m].
  auto maskFrom4 = [&](const float4* q) -> u64 {
    u64 e = 0;
#pragma unroll
    for (int j = 0; j < 4; ++j) {
      u64 b0 = __ballot(q[j].x > 0.0f);
      u64 b1 = __ballot(q[j].y > 0.0f);
      u64 b2 = __ballot(q[j].z > 0.0f);
      u64 b3 = __ballot(q[j].w > 0.0f);
      u64 s01 = (l15 & 1) ? b1 : b0;
      u64 s23 = (l15 & 1) ? b3 : b2;
      u64 bsel = (l15 & 2) ? s23 : s01;
      u64 ej = bsel >> (l15 >> 2);
      e = (kq == j) ? ej : e;
    }
    return e;
  };

  stageB(0, 0);

  // ---- prologue: build mask for tile 0 ----
  u64 wm[4];
  {
    float4 gp[8];
#pragma unroll
    for (int c = 0; c < 8; ++c) issueGf(gp + c, 0, c);   // chunks 0..7 (1 each)
    wm[0] = maskFrom4(gp);
    wm[1] = maskFrom4(gp + 4);
#pragma unroll
    for (int c = 0; c < 8; ++c) issueGf(gp + c, 0, 8 + c);
    wm[2] = maskFrom4(gp);
    wm[3] = maskFrom4(gp + 4);
  }
  asm volatile("s_waitcnt vmcnt(0)" ::: "memory");
  __builtin_amdgcn_s_barrier();

  f32x4 acc[4][4];
  float Sa[16], Pa[16], Ca[16];
  u64 wn[4];
  float4 gvA[4], gvB[4];
#pragma unroll
  for (int i = 0; i < 16; ++i) { Sa[i] = 0.0f; Pa[i] = 0.0f; Ca[i] = 0.0f; }

#define STEP(KK)                                                               \
  do {                                                                         \
    if ((KK) == 0) {                                                           \
      _Pragma("unroll") for (int m = 0; m < 4; ++m)                            \
          _Pragma("unroll") for (int n = 0; n < 4; ++n)                        \
              acc[m][n] = (f32x4)(0.0f);                                       \
      if (t < NT - 1) issueGf(gvA, t + 1, 0);                                  \
    }                                                                          \
    if ((KK) == 1 && t < NT - 1) issueGf(gvB, t + 1, 4);                       \
    f16x8 af[4], bf[4];                                                        \
    bf[0] = *(const f16x8*)(bp0 + (KK) * 32 + kq * 8);                         \
    bf[1] = *(const f16x8*)(bp1 + (KK) * 32 + kq * 8);                         \
    bf[2] = *(const f16x8*)(bp2 + (KK) * 32 + kq * 8);                         \
    bf[3] = *(const f16x8*)(bp3 + (KK) * 32 + kq * 8);                         \
    _Pragma("unroll") for (int m = 0; m < 4; ++m) {                            \
      int row = wr * 64 + m * 16 + l15;                                        \
      int cbP = ((KK) * 4 + kq) ^ (row & 7);                                   \
      af[m] = *(const f16x8*)&Asf[(size_t)row * 256 + cbP * 8];                \
    }                                                                          \
    _Pragma("unroll") for (int m = 0; m < 4; ++m)                              \
        _Pragma("unroll") for (int n = 0; n < 4; ++n)                          \
            acc[m][n] = __builtin_amdgcn_mfma_f32_16x16x32_f16(                \
                af[m], bf[n], acc[m][n], 0, 0, 0);                             \
    if ((KK) == 3 && t < NT - 1) {                                             \
      wn[0] = maskFrom4(gvA);                                                  \
      issueGf(gvA, t + 1, 8);                                                  \
    }                                                                          \
    if ((KK) == 4 && t < NT - 1) {                                             \
      wn[1] = maskFrom4(gvB);                                                  \
      issueGf(gvB, t + 1, 12);                                                 \
    }                                                                          \
    if ((KK) == 6 && t < NT - 1) wn[2] = maskFrom4(gvA);                       \
    if ((KK) == 7) {                                                           \
      if (t < NT - 1) wn[3] = maskFrom4(gvB);                                  \
      int ct0 = col0 + t * BN;                                                 \
      _Pragma("unroll") for (int m = 0; m < 4; ++m) {                          \
        int gi = row0 + wr * 64 + m * 16 + kq * 4;                             \
        _Pragma("unroll") for (int n = 0; n < 4; ++n) {                        \
          int gj = ct0 + wc * 64 + n * 16 + l15;                               \
          _Pragma("unroll") for (int r = 0; r < 4; ++r) {                      \
            float sim = acc[m][n][r] * INV_T;                                  \
            bool pos = (((unsigned)(wm[m] >> (r * 16 + n * 4)) & 1u) != 0u) || \
                       ((gi + r) == gj);                                       \
            float e = __expf(sim);                                             \
            int idx = m * 4 + r;                                               \
            Sa[idx] += pos ? 1.0f : e;                                         \
            Pa[idx] += pos ? sim : 0.0f;                                       \
            Ca[idx] += pos ? 1.0f : 0.0f;                                      \
          }                                                                    \
        }                                                                      \
      }                                                                        \
      if (t < NT - 1) {                                                        \
        _Pragma("unroll") for (int i = 0; i < 4; ++i) wm[i] = wn[i];           \
      }                                                                        \
    }                                                                          \
    if (t < NT - 1 || (KK) < 7) stageB(((KK) + 1) & 1, t * 8 + (KK) + 1);      \
    if ((KK) < 4) {                                                            \
      if (t < NT - 1)                                                          \
        asm volatile("s_waitcnt vmcnt(4)" ::: "memory");                       \
      else                                                                     \
        asm volatile("s_waitcnt vmcnt(0)" ::: "memory");                       \
    } else {                                                                   \
      asm volatile("s_waitcnt vmcnt(0)" ::: "memory");                         \
    }                                                                          \
    __builtin_amdgcn_s_barrier();                                              \
  } while (0)

#pragma unroll 1
  for (int t = 0; t < NT; ++t) {
    const _Float16* brow = zf + (size_t)(col0 + t * BN + wc * 64 + l15) * DIM;
    (void)brow;
    const _Float16* bp0;
    const _Float16* bp1;
    const _Float16* bp2;
    const _Float16* bp3;
    {
      int cur = 0;  // B comes from LDS buffers, indexed per-step below
      (void)cur;
    }
    // B fragment pointers into the LDS buffer for this step are computed
    // per-step from Bs[(step)&1]; macro uses bp0..bp3 bound here:
    // bind to buffer 0/1 alternating inside STEP via these per-row bases.
    // row layout in Bs: row*32 + phase*8 (XOR swizzled).
    // We re-derive them each STEP from the step parity:
#define BSETP(KK)                                                              \
    bp0 = &Bs[((t * 8 + (KK)) & 1)][( (size_t)(wc * 64 + 0 * 16 + l15) ) * 32];\
    bp1 = &Bs[((t * 8 + (KK)) & 1)][( (size_t)(wc * 64 + 1 * 16 + l15) ) * 32];\
    bp2 = &Bs[((t * 8 + (KK)) & 1)][( (size_t)(wc * 64 + 2 * 16 + l15) ) * 32];\
    bp3 = &Bs[((t * 8 + (KK)) & 1)][( (size_t)(wc * 64 + 3 * 16 + l15) ) * 32];

    // apply XOR-swizzle phase on read: phase = kq ^ ((row>>1)&3)
#define BREADP(P)  ((size_t)((kq ^ (((wc * 64 + (P) * 16 + l15) >> 1) & 3)) * 8))
#undef  BSETP
#define STEPB(KK)                                                              \
    bp0 = &Bs[((KK) & 1)][(size_t)(wc * 64 + 0 * 16 + l15) * 32 + BREADP(0)];  \
    bp1 = &Bs[((KK) & 1)][(size_t)(wc * 64 + 1 * 16 + l15) * 32 + BREADP(1)];  \
    bp2 = &Bs[((KK) & 1)][(size_t)(wc * 64 + 2 * 16 + l15) * 32 + BREADP(2)];  \
    bp3 = &Bs[((KK) & 1)][(size_t)(wc * 64 + 3 * 16 + l15) * 32 + BREADP(3)];

    // NOTE: bf[] reads in STEP use (bpX + KK*32 + kq*8); since the swizzle
    // phase is already folded into bpX here, subtract the kq*8 term by
    // binding bpX to base - kq*8 + phase*8:
#undef STEPB
    const int ph0 = (kq ^ (((wc * 64 + 0 * 16 + l15) >> 1) & 3)) - kq;
    const int ph1 = (kq ^ (((wc * 64 + 1 * 16 + l15) >> 1) & 3)) - kq;
    const int ph2 = (kq ^ (((wc * 64 + 2 * 16 + l15) >> 1) & 3)) - kq;
    const int ph3 = (kq ^ (((wc * 64 + 3 * 16 + l15) >> 1) & 3)) - kq;
    const _Float16* b0base = &Bs[0][(size_t)(wc * 64 + 0 * 16 + l15) * 32 + ph0 * 8];
    const _Float16* b1base = &Bs[0][(size_t)(wc * 64 + 1 * 16 + l15) * 32 + ph1 * 8];
    const _Float16* b2base = &Bs[0][(size_t)(wc * 64 + 2 * 16 + l15) * 32 + ph2 * 8];
    const _Float16* b3base = &Bs[0][(size_t)(wc * 64 + 3 * 16 + l15) * 32 + ph3 * 8];
    const size_t bufoff = (size_t)BN * 32;   // elements per buffer

    bp0 = b0base; bp1 = b1base; bp2 = b2base; bp3 = b3base;
    STEP(0);
    bp0 = b0base + bufoff; bp1 = b1base + bufoff; bp2 = b2base + bufoff; bp3 = b3base + bufoff;
    STEP(1);
    bp0 = b0base; bp1 = b1base; bp2 = b2base; bp3 = b3base;
    STEP(2);
    bp0 = b0base + bufoff; bp1 = b1base + bufoff; bp2 = b2base + bufoff; bp3 = b3base + bufoff;
    STEP(3);
    bp0 = b0base; bp1 = b1base; bp2 = b2base; bp3 = b3base;
    STEP(4);
    bp0 = b0base + bufoff; bp1 = b1base + bufoff; bp2 = b2base + bufoff; bp3 = b3base + bufoff;
    STEP(5);
    bp0 = b0base; bp1 = b1base; bp2 = b2base; bp3 = b3base;
    STEP(6);
    bp0 = b0base + bufoff; bp1 = b1base + bufoff; bp2 = b2base + bufoff; bp3 = b3base + bufoff;
    STEP(7);
  }
#undef STEP

  // ---- reduce across the 16 column-lanes of each row group ----
#pragma unroll
  for (int off = 1; off <= 8; off <<= 1) {
#pragma unroll
    for (int i = 0; i < 16; ++i) {
      Sa[i] += __shfl_xor(Sa[i], off);
      Pa[i] += __shfl_xor(Pa[i], off);
      Ca[i] += __shfl_xor(Ca[i], off);
    }
  }
  const int slot = cb * 2 + wc;
#pragma unroll
  for (int i = 0; i < 16; ++i) {
    if (l15 == i) {
      int m = i >> 2, r = i & 3;
      int row = row0 + wr * 64 + m * 16 + kq * 4 + r;
      Sp[(size_t)slot * NROW + row] = Sa[i];
      Pp[(size_t)slot * NROW + row] = Pa[i];
      Cp[(size_t)slot * NROW + row] = Ca[i];
    }
  }
}

// ---------------- per-row loss + block partials (deterministic) ----------------
__global__ __launch_bounds__(256) void loss_partial_kernel(
    const float* __restrict__ Sp, const float* __restrict__ Pp,
    const float* __restrict__ Cp, float* __restrict__ bsum) {
  int row = blockIdx.x * 256 + threadIdx.x;
  float S = 0.0f, P = 0.0f, C = 0.0f;
#pragma unroll
  for (int s2 = 0; s2 < 16; ++s2) {
    S += Sp[(size_t)s2 * NROW + row];
    P += Pp[(size_t)s2 * NROW + row];
    C += Cp[(size_t)s2 * NROW + row];
  }
  float pos = P / (C + 1e-8f);
  float contrib = __logf(S + __expf(pos)) - pos;
#pragma unroll
  for (int off = 1; off < 64; off <<= 1) contrib += __shfl_xor(contrib, off);
  __shared__ float wsum[4];
  if ((threadIdx.x & 63) == 0) wsum[threadIdx.x >> 6] = contrib;
  __syncthreads();
  if (threadIdx.x == 0) bsum[blockIdx.x] = wsum[0] + wsum[1] + wsum[2] + wsum[3];
}

__global__ void loss_final_kernel(const float* __restrict__ bsum, float* __restrict__ out) {
  int lane = threadIdx.x;
  float v = (lane < 32) ? bsum[lane] : 0.0f;
#pragma unroll
  for (int off = 1; off < 64; off <<= 1) v += __shfl_xor(v, off);
  if (lane == 0) out[0] = v / (float)NROW;
}

extern "C" void kernel_launch(void* const* d_in, const int* in_sizes, int n_in,
                              void* d_out, int out_size, void* d_ws, size_t ws_size,
                              hipStream_t stream) {
  const float* zv = (const float*)d_in[0];
  const float* zf = (const float*)d_in[1];
  const float* Gf = (const float*)d_in[2];
  float* out = (float*)d_out;

  char* ws = (char*)d_ws;
  _Float16* zv16 = (_Float16*)ws;
  _Float16* zf16 = zv16 + (size_t)NROW * DIM;
  float* Sp = (float*)(ws + 2 * (size_t)NROW * DIM * sizeof(_Float16));
  float* Pp = Sp + 16 * (size_t)NROW;
  float* Cp = Pp + 16 * (size_t)NROW;
  float* bsum = Cp + 16 * (size_t)NROW;

  norm_kernel<<<dim3(NROW / 4, 2), 256, 0, stream>>>(zv, zf, zv16, zf16);
  fused_kernel<<<512, 256, 0, stream>>>(zv16, zf16, Gf, Sp, Pp, Cp);
  loss_partial_kernel<<<NROW / 256, 256, 0, stream>>>(Sp, Pp, Cp, bsum);
  loss_final_kernel<<<1, 64, 0, stream>>>(bsum, out);
}